// Round 9
// baseline (274.362 us; speedup 1.0000x reference)
//
#include <hip/hip_runtime.h>

// GRU autoregressive decoder, bf16-MFMA persistent-weight, 16-wave blocks.
// B=16384, I=32, H=128, 30 steps, x0 = x[:,30,:], y feeds back as x.
//
// Round 13 = Round 12 resubmitted: R12's bench died in the harness
// ("container failed twice") before the kernel ever ran — no verdict.
// Design (unchanged):
//  * R11 post-mortem: every targeted counter improved (bank conflicts -96%,
//    VALU -8pp, no spill) yet time identical to R6 (106us). Per-step pipe
//    demand sums to ~3.2K cyc/SIMD vs 8.5K observed -> latency-bound with
//    only 2 waves/SIMD. Second-workgroup attempts (R7-R9) never co-resided
//    or spilled. A single 1024-thread workgroup CANNOT fail to co-reside:
//    16 waves = 4 waves/SIMD guaranteed at launch.
//  * BM stays 64, grid stays 256 (all CUs busy). Wave w: col-tile ct=w&7,
//    row-half rh=w>>3 -> 32 rows x 16 cols of gates (2 mt). Per-wave work
//    halves; wave-level overlap doubles.
//  * VGPR: 4 waves/SIMD -> hard 128 cap ((1024,1) under both launch_bounds
//    semantics). hst halves to 8; Wout B-frags live in LDS (R7's verified
//    sWo pattern) freeing 16 regs -> ~105 steady VGPR, no steady spill.
//  * Phase 2 (y-proj): 8 tiles (4 rowtiles x 2 coltiles) on waves 0-7;
//    waves 8-15 go straight to next phase 1. Same 1-barrier/step invariant.
//  * Keeps R11: XOR-swizzled shb (elem (r,c) at byte r*256+((2c)^((r&15)<<4))),
//    exp2-prescaled activations, v_cvt_pk_bf16_f32 h'-stores, LDS-only
//    barrier (no vmcnt drain), folded recurrence (Wstar/bstar in d_ws),
//    peeled step 0 with real x0, step loop unrolled x2 (literal buf index).

#define NB    16384
#define TT    60
#define II    32
#define HH    128
#define NSTEP 30
#define SEQ0  30
#define BM    64
#define XBS   40            // bf16 x-row stride (step-0 x0 only)
#define ROWB  256           // shb row bytes (128 bf16, pow2)
#define BUFB  (BM * ROWB)   // 16384 B per h buffer

// d_ws layout (floats): Wstar[384][128] at 0, bstar[384] at 49152.
// PRE-SCALED: r,z rows by -log2e, ni rows by +2log2e (exp2-form activations).
#define WS_WSTAR 0
#define WS_BSTAR (384 * 128)

#define S_RZ (-1.4426950408889634f)   // -log2(e)
#define S_N  ( 2.8853900817779268f)   // +2*log2(e)

typedef __attribute__((ext_vector_type(8))) short bf16x8;
typedef __attribute__((ext_vector_type(4))) float f32x4;

#define MFMA(a, b, c) __builtin_amdgcn_mfma_f32_16x16x32_bf16((a), (b), (c), 0, 0, 0)

// LDS-only barrier: wait DS ops, sync, pin scheduler (guide rule #18).
#define LDS_BARRIER() do {                                          \
    asm volatile("s_waitcnt lgkmcnt(0)\n\ts_barrier" ::: "memory"); \
    __builtin_amdgcn_sched_barrier(0);                              \
} while (0)

#define EXP2(x) __builtin_amdgcn_exp2f(x)
#define RCP(x)  __builtin_amdgcn_rcpf(x)

__device__ __forceinline__ short f2bf(float x) {  // RNE fp32->bf16 (init paths)
    unsigned u = __float_as_uint(x);
    u += 0x7FFFu + ((u >> 16) & 1u);
    return (short)(u >> 16);
}
__device__ __forceinline__ unsigned cvt_pk_bf16(float lo, float hi) {
    unsigned r;  // D[15:0]=bf16(S0) RNE, D[31:16]=bf16(S1)
    asm("v_cvt_pk_bf16_f32 %0, %1, %2" : "=v"(r) : "v"(lo), "v"(hi));
    return r;
}
__device__ __forceinline__ bf16x8 ldw8(const float* p) {  // 8 fp32 -> bf16x8
    float4 a = *(const float4*)p;
    float4 b = *(const float4*)(p + 4);
    bf16x8 f;
    f[0] = f2bf(a.x); f[1] = f2bf(a.y); f[2] = f2bf(a.z); f[3] = f2bf(a.w);
    f[4] = f2bf(b.x); f[5] = f2bf(b.y); f[6] = f2bf(b.z); f[7] = f2bf(b.w);
    return f;
}
__device__ __forceinline__ bf16x8 ldw8s(const float* p, float s) {  // scaled
    float4 a = *(const float4*)p;
    float4 b = *(const float4*)(p + 4);
    bf16x8 f;
    f[0] = f2bf(a.x * s); f[1] = f2bf(a.y * s); f[2] = f2bf(a.z * s); f[3] = f2bf(a.w * s);
    f[4] = f2bf(b.x * s); f[5] = f2bf(b.y * s); f[6] = f2bf(b.z * s); f[7] = f2bf(b.w * s);
    return f;
}
// ap = -log2e * a  ->  sigmoid(a) = rcp(1 + 2^ap)
__device__ __forceinline__ float sigm2(float ap) { return RCP(1.0f + EXP2(ap)); }
// tp = 2*log2e * t ->  tanh(t) = 1 - 2*rcp(1 + 2^tp)
__device__ __forceinline__ float tanh2(float tp) {
    return fmaf(-2.0f, RCP(1.0f + EXP2(tp)), 1.0f);
}

// ---- prep: folded weights, PRE-SCALED for exp2-form activations ----
__global__ void fold_kernel(const float* __restrict__ Wih,
                            const float* __restrict__ Whh,
                            const float* __restrict__ bih,
                            const float* __restrict__ bhh,
                            const float* __restrict__ Wout,
                            const float* __restrict__ bout,
                            float* __restrict__ ws)
{
    const int jg = blockIdx.x;     // 0..383 = gate*128 + j
    const int k  = threadIdx.x;    // 0..127
    const int gate = jg >> 7;
    const float sc = (gate < 2) ? S_RZ : S_N;
    float acc  = (gate < 2) ? Whh[(size_t)jg * HH + k] : 0.0f;
    float bacc = 0.0f;
    #pragma unroll 8
    for (int i = 0; i < II; ++i) {
        const float w = Wih[(size_t)jg * II + i];
        acc  += w * Wout[(size_t)i * HH + k];
        bacc += w * bout[i];
    }
    ws[WS_WSTAR + (size_t)jg * HH + k] = acc * sc;
    if (k == 0)
        ws[WS_BSTAR + jg] = (bih[jg] + ((gate < 2) ? bhh[jg] : 0.0f) + bacc) * sc;
}

__global__ __launch_bounds__(1024, 1)
void gru_mfma_kernel(const float* __restrict__ x,
                     const float* __restrict__ h0,
                     const float* __restrict__ Wih,
                     const float* __restrict__ Whh,
                     const float* __restrict__ bih,
                     const float* __restrict__ bhh,
                     const float* __restrict__ Wout,
                     const float* __restrict__ bout,
                     const float* __restrict__ ws,
                     float* __restrict__ out)
{
    __shared__ short shb[2][BM * 128];     // bf16 h, double-buffered, 32 KB,
                                           // XOR-swizzled as in R11
    __shared__ short sxb[BM * XBS];        // bf16 x0 (step 0 only, 5 KB)
    __shared__ short sWo[2 * 4 * 64 * 8];  // Wout B-frags, 8 KB
    char* shbb = (char*)shb;

    const int tid    = threadIdx.x;
    const int lane   = tid & 63;
    const int wave   = __builtin_amdgcn_readfirstlane(tid >> 6);  // 0..15
    const int n16    = lane & 15;   // MFMA col / A-row index
    const int quad   = lane >> 4;   // MFMA k-group / D-row group
    const int rowblk = blockIdx.x * BM;
    const int ct     = wave & 7;    // col-tile: gate cols [16ct,16ct+16)
    const int rh     = wave >> 3;   // row-half: rows [32rh,32rh+32)
    const int j      = ct * 16 + n16;   // this lane's gate column

    // ---- swizzled LDS lane bases (prologue-only VALU) ----
    // phase-1 read: row = rh*32 + mt*16 + n16 (row&15 == n16):
    int rb[4];
    #pragma unroll
    for (int kt = 0; kt < 4; ++kt)
        rb[kt] = rh * 8192 + n16 * 256 + ((kt * 64 + quad * 16) ^ (n16 << 4));
    // h' write: row = rh*32 + mt*16 + quad*4 + rg, col j (row&15 = quad*4+rg):
    int wb[4];
    #pragma unroll
    for (int rg = 0; rg < 4; ++rg)
        wb[rg] = rh * 8192 + quad * 1024 + ((2 * j) ^ (quad << 6) ^ (rg << 4));
    // phase-2 read (waves 0-7): row = rowtile*16 + n16:
    const int rowtile = (wave >> 1) & 3;  // 0..3: which 16 rows of the 64
    const int coltile = wave & 1;         // 0/1:  which 16 output cols
    int rb2[4];
    #pragma unroll
    for (int kt = 0; kt < 4; ++kt)
        rb2[kt] = rowtile * 4096 + n16 * 256 + ((kt * 64 + quad * 16) ^ (n16 << 4));

    // ---- persistent n-gate h-weights, scaled by 2log2e ----
    bf16x8 Bnh[4];
    float  b_nh;
    {
        const float* wn = Whh + (size_t)(2 * HH + j) * HH;
        #pragma unroll
        for (int kt = 0; kt < 4; ++kt)
            Bnh[kt] = ldw8s(wn + kt * 32 + quad * 8, S_N);
        b_nh = bhh[2 * HH + j] * S_N;
    }
    // ---- Wout frags -> LDS (waves 0-1 stage coltile=wave's fragments) ----
    if (wave < 2) {
        #pragma unroll
        for (int kt = 0; kt < 4; ++kt) {
            bf16x8 t = ldw8(Wout + (size_t)(wave * 16 + n16) * HH + kt * 32 + quad * 8);
            *(bf16x8*)&sWo[((wave * 4 + kt) * 64 + lane) * 8] = t;
        }
    }
    const float b_o = bout[coltile * 16 + n16];

    // ---- lane-private fp32 h-state: hst[mt][reg] = h[row][j],
    //      row = rh*32 + mt*16 + quad*4 + reg ----
    float hst[2][4];
    #pragma unroll
    for (int mt = 0; mt < 2; ++mt)
        #pragma unroll
        for (int reg = 0; reg < 4; ++reg)
            hst[mt][reg] =
                h0[(size_t)(rowblk + rh * 32 + mt * 16 + quad * 4 + reg) * HH + j];

    // ---- strength-reduced out pointers (waves 0-7 use them) ----
    float* yp0;
    float* yp1;
    {
        const int r0 = rowblk + rowtile * 16 + quad * 4;
        yp0 = out + (size_t)r0 * (NSTEP * II) + coltile * 16 + n16;
        yp1 = yp0 + 2 * (size_t)(NSTEP * II);
    }

    // ---- stage bf16 h0 (swizzled) and x0 into LDS ----
    {
        const int r  = tid >> 4;            // 64 rows, 16 threads/row
        const int cb = (tid & 15) * 16;     // byte col offset (8 cols)
        const int sw = (r & 15) << 4;
        *(bf16x8*)(shbb + r * ROWB + (cb ^ sw)) =
            ldw8(h0 + (size_t)(rowblk + r) * HH + (tid & 15) * 8);
    }
    if (tid < 256) {
        const int r  = tid >> 2;            // 64 rows, 4 threads/row
        const int c0 = (tid & 3) * 8;
        *(bf16x8*)&sxb[r * XBS + c0] = ldw8(x + ((size_t)(rowblk + r) * TT + SEQ0) * II + c0);
    }
    __syncthreads();

    // ================= peeled step 0: un-folded (scaled) weights + x0 =====
    {
        bf16x8 Br0[4], Bz0[4], Bxr, Bxz, Bxn;
        const float* wr = Whh + (size_t)j * HH;
        const float* wz = Whh + (size_t)(HH + j) * HH;
        #pragma unroll
        for (int kt = 0; kt < 4; ++kt) {
            Br0[kt] = ldw8s(wr + kt * 32 + quad * 8, S_RZ);
            Bz0[kt] = ldw8s(wz + kt * 32 + quad * 8, S_RZ);
        }
        Bxr = ldw8s(Wih + (size_t)j * II + quad * 8, S_RZ);
        Bxz = ldw8s(Wih + (size_t)(HH + j) * II + quad * 8, S_RZ);
        Bxn = ldw8s(Wih + (size_t)(2 * HH + j) * II + quad * 8, S_N);
        const float b_r0 = (bih[j] + bhh[j]) * S_RZ;
        const float b_z0 = (bih[HH + j] + bhh[HH + j]) * S_RZ;
        const float b_n0 = bih[2 * HH + j] * S_N;

        #pragma unroll
        for (int mt = 0; mt < 2; ++mt) {
            f32x4 ar  = (f32x4){b_r0, b_r0, b_r0, b_r0};
            f32x4 az  = (f32x4){b_z0, b_z0, b_z0, b_z0};
            f32x4 anh = (f32x4){b_nh, b_nh, b_nh, b_nh};
            f32x4 anx = (f32x4){b_n0, b_n0, b_n0, b_n0};
            #pragma unroll
            for (int kt = 0; kt < 4; ++kt) {
                bf16x8 A = *(const bf16x8*)(shbb + rb[kt] + mt * 4096);
                ar  = MFMA(A, Br0[kt], ar);
                az  = MFMA(A, Bz0[kt], az);
                anh = MFMA(A, Bnh[kt], anh);
            }
            {
                bf16x8 Ax = *(const bf16x8*)&sxb[(rh * 32 + mt * 16 + n16) * XBS + quad * 8];
                ar  = MFMA(Ax, Bxr, ar);
                az  = MFMA(Ax, Bxz, az);
                anx = MFMA(Ax, Bxn, anx);
            }
            float hn[4];
            #pragma unroll
            for (int reg = 0; reg < 4; ++reg) {
                const float r = sigm2(ar[reg]);
                const float z = sigm2(az[reg]);
                const float n = tanh2(anx[reg] + r * anh[reg]);
                const float hnew = n + z * (hst[mt][reg] - n);
                hst[mt][reg] = hnew;
                hn[reg] = hnew;
            }
            const unsigned pk01 = cvt_pk_bf16(hn[0], hn[1]);
            const unsigned pk23 = cvt_pk_bf16(hn[2], hn[3]);
            *(short*)(shbb + BUFB + wb[0] + mt * 4096)       = (short)pk01;
            *(short*)(shbb + BUFB + wb[1] + mt * 4096 + 256) = (short)(pk01 >> 16);
            *(short*)(shbb + BUFB + wb[2] + mt * 4096 + 512) = (short)pk23;
            *(short*)(shbb + BUFB + wb[3] + mt * 4096 + 768) = (short)(pk23 >> 16);
        }
    }

    // ---- folded steady-state weights (pre-scaled in ws) ----
    bf16x8 Brs[4], Bzs[4], Bni[4];
    float  b_rs, b_zs, b_ni;
    {
        const float* pr = ws + WS_WSTAR + (size_t)j * HH;
        const float* pz = ws + WS_WSTAR + (size_t)(HH + j) * HH;
        const float* pn = ws + WS_WSTAR + (size_t)(2 * HH + j) * HH;
        #pragma unroll
        for (int kt = 0; kt < 4; ++kt) {
            Brs[kt] = ldw8(pr + kt * 32 + quad * 8);
            Bzs[kt] = ldw8(pz + kt * 32 + quad * 8);
            Bni[kt] = ldw8(pn + kt * 32 + quad * 8);
        }
        b_rs = ws[WS_BSTAR + j];
        b_zs = ws[WS_BSTAR + HH + j];
        b_ni = ws[WS_BSTAR + 2 * HH + j];
    }

    __syncthreads();   // step-0 h' (and sWo) visible to all 16 waves

    // ================= steps: {phase2(s) || phase1(s+1)}, 1 barrier/step ===
    // body(qb): h_{s+1} in shb[qb]. Phase 2 (waves 0-7) reads shb[qb];
    // phase 1 of step s+1 reads shb[qb], writes shb[qb^1] — disjoint.
    auto body = [&](int qb, bool last) {
        const int rdoff = qb * BUFB;
        // ---- phase 2: y_s = h_{s+1} @ Wout^T + bout (waves 0-7) ----
        if (wave < 8) {
            f32x4 yo = (f32x4){b_o, b_o, b_o, b_o};
            #pragma unroll
            for (int kt = 0; kt < 4; ++kt) {
                bf16x8 A2  = *(const bf16x8*)(shbb + rdoff + rb2[kt]);
                bf16x8 Bof = *(const bf16x8*)&sWo[((coltile * 4 + kt) * 64 + lane) * 8];
                yo = MFMA(A2, Bof, yo);
            }
            yp0[0]        = yo[0];
            yp0[NSTEP*II] = yo[1];
            yp1[0]        = yo[2];
            yp1[NSTEP*II] = yo[3];
            yp0 += II;
            yp1 += II;
        }
        if (last) return;

        // ---- phase 1: h_{s+2} from h_{s+1} (folded, K=128) ----
        const int wroff = (qb ^ 1) * BUFB;
        #pragma unroll
        for (int mt = 0; mt < 2; ++mt) {
            f32x4 ar  = (f32x4){b_rs, b_rs, b_rs, b_rs};
            f32x4 az  = (f32x4){b_zs, b_zs, b_zs, b_zs};
            f32x4 anh = (f32x4){b_nh, b_nh, b_nh, b_nh};
            f32x4 ani = (f32x4){b_ni, b_ni, b_ni, b_ni};
            #pragma unroll
            for (int kt = 0; kt < 4; ++kt) {       // 4 indep acc chains
                bf16x8 A = *(const bf16x8*)(shbb + rdoff + rb[kt] + mt * 4096);
                ar  = MFMA(A, Brs[kt], ar);
                az  = MFMA(A, Bzs[kt], az);
                anh = MFMA(A, Bnh[kt], anh);
                ani = MFMA(A, Bni[kt], ani);
            }
            float hn[4];
            #pragma unroll
            for (int reg = 0; reg < 4; ++reg) {
                const float r = sigm2(ar[reg]);
                const float z = sigm2(az[reg]);
                const float n = tanh2(ani[reg] + r * anh[reg]);
                const float hnew = n + z * (hst[mt][reg] - n);
                hst[mt][reg] = hnew;
                hn[reg] = hnew;
            }
            const unsigned pk01 = cvt_pk_bf16(hn[0], hn[1]);
            const unsigned pk23 = cvt_pk_bf16(hn[2], hn[3]);
            *(short*)(shbb + wroff + wb[0] + mt * 4096)       = (short)pk01;
            *(short*)(shbb + wroff + wb[1] + mt * 4096 + 256) = (short)(pk01 >> 16);
            *(short*)(shbb + wroff + wb[2] + mt * 4096 + 512) = (short)pk23;
            *(short*)(shbb + wroff + wb[3] + mt * 4096 + 768) = (short)(pk23 >> 16);
        }
        LDS_BARRIER();
    };

    for (int s2 = 0; s2 < NSTEP - 2; s2 += 2) {   // s = 0..27
        body(1, false);
        body(0, false);
    }
    body(1, false);   // s = 28
    body(0, true);    // s = 29: final Y only
}

extern "C" void kernel_launch(void* const* d_in, const int* in_sizes, int n_in,
                              void* d_out, int out_size, void* d_ws, size_t ws_size,
                              hipStream_t stream) {
    (void)in_sizes; (void)n_in; (void)out_size; (void)ws_size;
    const float* x    = (const float*)d_in[0];
    const float* h0   = (const float*)d_in[1];
    const float* Wih  = (const float*)d_in[2];
    const float* Whh  = (const float*)d_in[3];
    const float* bih  = (const float*)d_in[4];
    const float* bhh  = (const float*)d_in[5];
    const float* Wout = (const float*)d_in[6];
    const float* bout = (const float*)d_in[7];
    float* out = (float*)d_out;
    float* ws  = (float*)d_ws;

    fold_kernel<<<dim3(384), dim3(128), 0, stream>>>(Wih, Whh, bih, bhh,
                                                     Wout, bout, ws);
    dim3 grid(NB / BM);   // 256 blocks x 1024 thr -> 16 waves/CU guaranteed
    dim3 block(1024);
    gru_mfma_kernel<<<grid, block, 0, stream>>>(x, h0, Wih, Whh, bih, bhh,
                                                Wout, bout, ws, out);
}

// Round 10
// 256.078 us; speedup vs baseline: 1.0714x; 1.0714x over previous
//
#include <hip/hip_runtime.h>

// GRU autoregressive decoder, bf16-MFMA persistent-weight, 8-wave blocks.
// B=16384, I=32, H=128, 30 steps, x0 = x[:,30,:], y feeds back as x.
//
// Round 13 -> 14 (force MFMA||VALU pipe overlap inside each wave):
//  * Evidence: R11 (-20% VALU) flat, R13 (2x resident waves) flat/worse ->
//    neither work nor occupancy is the limiter. Corrected MFMA model:
//    16x16x32 bf16 occupies its SIMD's matrix pipe ~19.4 cyc (844 FLOP/cyc/
//    SIMD), so per step per SIMD: MFMA ~2.6K cyc + VALU ~3.2K cyc ~= the
//    8.5K observed MINUS overlap: the compiler's per-mt [read->MFMA->act]
//    schedule runs the two pipes strictly serially, both waves in lockstep.
//  * Fix: software-pipeline the mt loop: MFMA(mt0); MFMA(mt1);
//    {ACT(mt0) || MFMA(mt2)}; {ACT(mt1) || MFMA(mt3)}; ACT(mt2); ACT(mt3),
//    with sched_barrier(0) separators so the scheduler keeps MFMA issue and
//    activation VALU co-present in each window. Floor if pipes overlap:
//    max(2.6K,3.2K) ~= 3.5-4K cyc/step -> ~50us.
//  * Bias-in-C: persistent f32x4 bias vectors as the MFMA C operand kill the
//    64 v_mov acc-inits per wave per step.
//  * VGPR rises to ~200 (2 live acc sets + 80 weight regs): fine under the
//    256-reg 2-wave/SIMD budget of (512,1). Spill tripwire = FETCH_SIZE.
//  * Keeps R11 (verified, 106us): XOR-swizzled shb, exp2-prescaled folded
//    weights, cvt_pk h'-stores, LDS-only barrier, peeled step 0, grid 256.

#define NB    16384
#define TT    60
#define II    32
#define HH    128
#define NSTEP 30
#define SEQ0  30
#define BM    64
#define XBS   40            // bf16 x-row stride (step-0 x0 only)
#define ROWB  256           // shb row bytes (128 bf16, pow2)
#define BUFB  (BM * ROWB)   // 16384 B per h buffer

// d_ws layout (floats): Wstar[384][128] at 0, bstar[384] at 49152.
// PRE-SCALED: r,z rows by -log2e, ni rows by +2log2e (exp2-form activations).
#define WS_WSTAR 0
#define WS_BSTAR (384 * 128)

#define S_RZ (-1.4426950408889634f)   // -log2(e)
#define S_N  ( 2.8853900817779268f)   // +2*log2(e)

typedef __attribute__((ext_vector_type(8))) short bf16x8;
typedef __attribute__((ext_vector_type(4))) float f32x4;

#define MFMA(a, b, c) __builtin_amdgcn_mfma_f32_16x16x32_bf16((a), (b), (c), 0, 0, 0)

// LDS-only barrier: wait DS ops, sync, pin scheduler (guide rule #18).
#define LDS_BARRIER() do {                                          \
    asm volatile("s_waitcnt lgkmcnt(0)\n\ts_barrier" ::: "memory"); \
    __builtin_amdgcn_sched_barrier(0);                              \
} while (0)

#define SB() __builtin_amdgcn_sched_barrier(0)

#define EXP2(x) __builtin_amdgcn_exp2f(x)
#define RCP(x)  __builtin_amdgcn_rcpf(x)

__device__ __forceinline__ short f2bf(float x) {  // RNE fp32->bf16 (init paths)
    unsigned u = __float_as_uint(x);
    u += 0x7FFFu + ((u >> 16) & 1u);
    return (short)(u >> 16);
}
__device__ __forceinline__ unsigned cvt_pk_bf16(float lo, float hi) {
    unsigned r;  // D[15:0]=bf16(S0) RNE, D[31:16]=bf16(S1)
    asm("v_cvt_pk_bf16_f32 %0, %1, %2" : "=v"(r) : "v"(lo), "v"(hi));
    return r;
}
__device__ __forceinline__ bf16x8 ldw8(const float* p) {  // 8 fp32 -> bf16x8
    float4 a = *(const float4*)p;
    float4 b = *(const float4*)(p + 4);
    bf16x8 f;
    f[0] = f2bf(a.x); f[1] = f2bf(a.y); f[2] = f2bf(a.z); f[3] = f2bf(a.w);
    f[4] = f2bf(b.x); f[5] = f2bf(b.y); f[6] = f2bf(b.z); f[7] = f2bf(b.w);
    return f;
}
__device__ __forceinline__ bf16x8 ldw8s(const float* p, float s) {  // scaled
    float4 a = *(const float4*)p;
    float4 b = *(const float4*)(p + 4);
    bf16x8 f;
    f[0] = f2bf(a.x * s); f[1] = f2bf(a.y * s); f[2] = f2bf(a.z * s); f[3] = f2bf(a.w * s);
    f[4] = f2bf(b.x * s); f[5] = f2bf(b.y * s); f[6] = f2bf(b.z * s); f[7] = f2bf(b.w * s);
    return f;
}
// ap = -log2e * a  ->  sigmoid(a) = rcp(1 + 2^ap)
__device__ __forceinline__ float sigm2(float ap) { return RCP(1.0f + EXP2(ap)); }
// tp = 2*log2e * t ->  tanh(t) = 1 - 2*rcp(1 + 2^tp)
__device__ __forceinline__ float tanh2(float tp) {
    return fmaf(-2.0f, RCP(1.0f + EXP2(tp)), 1.0f);
}

// ---- prep: folded weights, PRE-SCALED for exp2-form activations ----
__global__ void fold_kernel(const float* __restrict__ Wih,
                            const float* __restrict__ Whh,
                            const float* __restrict__ bih,
                            const float* __restrict__ bhh,
                            const float* __restrict__ Wout,
                            const float* __restrict__ bout,
                            float* __restrict__ ws)
{
    const int jg = blockIdx.x;     // 0..383 = gate*128 + j
    const int k  = threadIdx.x;    // 0..127
    const int gate = jg >> 7;
    const float sc = (gate < 2) ? S_RZ : S_N;
    float acc  = (gate < 2) ? Whh[(size_t)jg * HH + k] : 0.0f;
    float bacc = 0.0f;
    #pragma unroll 8
    for (int i = 0; i < II; ++i) {
        const float w = Wih[(size_t)jg * II + i];
        acc  += w * Wout[(size_t)i * HH + k];
        bacc += w * bout[i];
    }
    ws[WS_WSTAR + (size_t)jg * HH + k] = acc * sc;
    if (k == 0)
        ws[WS_BSTAR + jg] = (bih[jg] + ((gate < 2) ? bhh[jg] : 0.0f) + bacc) * sc;
}

// MFMAs for one 16-row m-tile: 4 K-tiles x {r,z,nh,ni}, bias vectors as C.
#define MT_MFMA(mt, ar, az, anh, ani, rdoff) do {                              \
    bf16x8 A0_ = *(const bf16x8*)(shbb + (rdoff) + rb[0] + (mt) * 4096);       \
    bf16x8 A1_ = *(const bf16x8*)(shbb + (rdoff) + rb[1] + (mt) * 4096);       \
    bf16x8 A2_ = *(const bf16x8*)(shbb + (rdoff) + rb[2] + (mt) * 4096);       \
    bf16x8 A3_ = *(const bf16x8*)(shbb + (rdoff) + rb[3] + (mt) * 4096);       \
    ar  = MFMA(A0_, Brs[0], vb_r);  az  = MFMA(A0_, Bzs[0], vb_z);             \
    anh = MFMA(A0_, Bnh[0], vb_nh); ani = MFMA(A0_, Bni[0], vb_ni);            \
    ar  = MFMA(A1_, Brs[1], ar);    az  = MFMA(A1_, Bzs[1], az);               \
    anh = MFMA(A1_, Bnh[1], anh);   ani = MFMA(A1_, Bni[1], ani);              \
    ar  = MFMA(A2_, Brs[2], ar);    az  = MFMA(A2_, Bzs[2], az);               \
    anh = MFMA(A2_, Bnh[2], anh);   ani = MFMA(A2_, Bni[2], ani);              \
    ar  = MFMA(A3_, Brs[3], ar);    az  = MFMA(A3_, Bzs[3], az);               \
    anh = MFMA(A3_, Bnh[3], anh);   ani = MFMA(A3_, Bni[3], ani);              \
} while (0)

// Activations + h-state update + swizzled h' store for one m-tile.
#define ACT_MT(mt, ar, az, anh, ani, wroff) do {                               \
    float hn_[4];                                                              \
    _Pragma("unroll")                                                          \
    for (int rg_ = 0; rg_ < 4; ++rg_) {                                        \
        const float r_ = sigm2((ar)[rg_]);                                     \
        const float z_ = sigm2((az)[rg_]);                                     \
        const float n_ = tanh2((ani)[rg_] + r_ * (anh)[rg_]);                  \
        const float h_ = n_ + z_ * (hst[mt][rg_] - n_);                        \
        hst[mt][rg_] = h_;                                                     \
        hn_[rg_] = h_;                                                         \
    }                                                                          \
    const unsigned pkA_ = cvt_pk_bf16(hn_[0], hn_[1]);                         \
    const unsigned pkB_ = cvt_pk_bf16(hn_[2], hn_[3]);                         \
    *(short*)(shbb + (wroff) + wb[0] + (mt) * 4096)       = (short)pkA_;       \
    *(short*)(shbb + (wroff) + wb[1] + (mt) * 4096 + 256) = (short)(pkA_ >> 16); \
    *(short*)(shbb + (wroff) + wb[2] + (mt) * 4096 + 512) = (short)pkB_;       \
    *(short*)(shbb + (wroff) + wb[3] + (mt) * 4096 + 768) = (short)(pkB_ >> 16); \
} while (0)

__global__ __launch_bounds__(512, 1)
void gru_mfma_kernel(const float* __restrict__ x,
                     const float* __restrict__ h0,
                     const float* __restrict__ Wih,
                     const float* __restrict__ Whh,
                     const float* __restrict__ bih,
                     const float* __restrict__ bhh,
                     const float* __restrict__ Wout,
                     const float* __restrict__ bout,
                     const float* __restrict__ ws,
                     float* __restrict__ out)
{
    __shared__ short shb[2][BM * 128];  // bf16 h, double-buffered, 32 KB,
                                        // XOR-swizzled: elem (r,c) at byte
                                        // r*256 + ((2c) ^ ((r&15)<<4))
    __shared__ short sxb[BM * XBS];     // bf16 x0 (step 0 only, 5.1 KB)
    char* shbb = (char*)shb;

    const int tid    = threadIdx.x;
    const int lane   = tid & 63;
    const int wave   = __builtin_amdgcn_readfirstlane(tid >> 6);  // 0..7
    const int n16    = lane & 15;   // MFMA col / A-row index
    const int quad   = lane >> 4;   // MFMA k-group / D-row group
    const int rowblk = blockIdx.x * BM;
    const int j      = wave * 16 + n16;   // hidden unit this lane's gate col

    // ---- swizzled LDS lane bases (prologue-only VALU) ----
    int rb[4];
    #pragma unroll
    for (int kt = 0; kt < 4; ++kt)
        rb[kt] = n16 * 256 + ((kt * 64 + quad * 16) ^ (n16 << 4));
    int wb[4];
    #pragma unroll
    for (int rg = 0; rg < 4; ++rg)
        wb[rg] = quad * 1024 + ((2 * j) ^ (quad << 6) ^ (rg << 4));

    // ---- persistent n-gate h-weights, scaled by 2log2e ----
    bf16x8 Bnh[4];
    float  b_nh;
    {
        const float* wn = Whh + (size_t)(2 * HH + j) * HH;
        #pragma unroll
        for (int kt = 0; kt < 4; ++kt)
            Bnh[kt] = ldw8s(wn + kt * 32 + quad * 8, S_N);
        b_nh = bhh[2 * HH + j] * S_N;
    }
    // ---- phase-2 tile assignment + this wave's Wout column-tile ----
    const int rowtile = wave >> 1;    // 0..3: which 16 rows of the 64
    const int coltile = wave & 1;     // 0/1:  which 16 output cols
    bf16x8 Bo[4];
    float  b_o;
    {
        const int i = coltile * 16 + n16;
        #pragma unroll
        for (int kt = 0; kt < 4; ++kt)
            Bo[kt] = ldw8(Wout + (size_t)i * HH + kt * 32 + quad * 8);
        b_o = bout[i];
    }

    // ---- lane-private fp32 h-state ----
    float hst[4][4];
    #pragma unroll
    for (int mt = 0; mt < 4; ++mt)
        #pragma unroll
        for (int reg = 0; reg < 4; ++reg)
            hst[mt][reg] = h0[(size_t)(rowblk + mt * 16 + quad * 4 + reg) * HH + j];

    // ---- strength-reduced out pointers: rows rowtile*16+quad*4+{0..3} ----
    float* yp0;
    float* yp1;
    {
        const int r0 = rowblk + rowtile * 16 + quad * 4;
        yp0 = out + (size_t)r0 * (NSTEP * II) + coltile * 16 + n16;
        yp1 = yp0 + 2 * (size_t)(NSTEP * II);
    }

    // ---- stage bf16 h0 (swizzled) and x0 into LDS ----
    {
        const int r  = tid >> 3;            // 64 rows, 8 threads/row
        const int cb = (tid & 7) * 32;      // byte col offset (16 cols)
        const int sw = (r & 15) << 4;
        const float* src = h0 + (size_t)(rowblk + r) * HH + (tid & 7) * 16;
        *(bf16x8*)(shbb + r * ROWB + (cb ^ sw))        = ldw8(src);
        *(bf16x8*)(shbb + r * ROWB + ((cb + 16) ^ sw)) = ldw8(src + 8);
    }
    if (tid < 256) {
        const int r  = tid >> 2;            // 64 rows, 4 threads/row
        const int c0 = (tid & 3) * 8;
        *(bf16x8*)&sxb[r * XBS + c0] = ldw8(x + ((size_t)(rowblk + r) * TT + SEQ0) * II + c0);
    }
    __syncthreads();

    // ================= peeled step 0: un-folded (scaled) weights + x0 =====
    {
        bf16x8 Br0[4], Bz0[4], Bxr, Bxz, Bxn;
        const float* wr = Whh + (size_t)j * HH;
        const float* wz = Whh + (size_t)(HH + j) * HH;
        #pragma unroll
        for (int kt = 0; kt < 4; ++kt) {
            Br0[kt] = ldw8s(wr + kt * 32 + quad * 8, S_RZ);
            Bz0[kt] = ldw8s(wz + kt * 32 + quad * 8, S_RZ);
        }
        Bxr = ldw8s(Wih + (size_t)j * II + quad * 8, S_RZ);
        Bxz = ldw8s(Wih + (size_t)(HH + j) * II + quad * 8, S_RZ);
        Bxn = ldw8s(Wih + (size_t)(2 * HH + j) * II + quad * 8, S_N);
        const float b_r0 = (bih[j] + bhh[j]) * S_RZ;
        const float b_z0 = (bih[HH + j] + bhh[HH + j]) * S_RZ;
        const float b_n0 = bih[2 * HH + j] * S_N;

        #pragma unroll
        for (int mt = 0; mt < 4; ++mt) {
            f32x4 ar  = (f32x4){b_r0, b_r0, b_r0, b_r0};
            f32x4 az  = (f32x4){b_z0, b_z0, b_z0, b_z0};
            f32x4 anh = (f32x4){b_nh, b_nh, b_nh, b_nh};
            f32x4 anx = (f32x4){b_n0, b_n0, b_n0, b_n0};
            #pragma unroll
            for (int kt = 0; kt < 4; ++kt) {
                bf16x8 A = *(const bf16x8*)(shbb + rb[kt] + mt * 4096);
                ar  = MFMA(A, Br0[kt], ar);
                az  = MFMA(A, Bz0[kt], az);
                anh = MFMA(A, Bnh[kt], anh);
            }
            {
                bf16x8 Ax = *(const bf16x8*)&sxb[(mt * 16 + n16) * XBS + quad * 8];
                ar  = MFMA(Ax, Bxr, ar);
                az  = MFMA(Ax, Bxz, az);
                anx = MFMA(Ax, Bxn, anx);
            }
            float hn[4];
            #pragma unroll
            for (int reg = 0; reg < 4; ++reg) {
                const float r = sigm2(ar[reg]);
                const float z = sigm2(az[reg]);
                const float n = tanh2(anx[reg] + r * anh[reg]);
                const float hnew = n + z * (hst[mt][reg] - n);
                hst[mt][reg] = hnew;
                hn[reg] = hnew;
            }
            const unsigned pk01 = cvt_pk_bf16(hn[0], hn[1]);
            const unsigned pk23 = cvt_pk_bf16(hn[2], hn[3]);
            *(short*)(shbb + BUFB + wb[0] + mt * 4096)       = (short)pk01;
            *(short*)(shbb + BUFB + wb[1] + mt * 4096 + 256) = (short)(pk01 >> 16);
            *(short*)(shbb + BUFB + wb[2] + mt * 4096 + 512) = (short)pk23;
            *(short*)(shbb + BUFB + wb[3] + mt * 4096 + 768) = (short)(pk23 >> 16);
        }
    }

    // ---- folded steady-state weights (pre-scaled in ws) ----
    bf16x8 Brs[4], Bzs[4], Bni[4];
    f32x4  vb_r, vb_z, vb_nh, vb_ni, vb_o;
    {
        const float* pr = ws + WS_WSTAR + (size_t)j * HH;
        const float* pz = ws + WS_WSTAR + (size_t)(HH + j) * HH;
        const float* pn = ws + WS_WSTAR + (size_t)(2 * HH + j) * HH;
        #pragma unroll
        for (int kt = 0; kt < 4; ++kt) {
            Brs[kt] = ldw8(pr + kt * 32 + quad * 8);
            Bzs[kt] = ldw8(pz + kt * 32 + quad * 8);
            Bni[kt] = ldw8(pn + kt * 32 + quad * 8);
        }
        const float b_rs = ws[WS_BSTAR + j];
        const float b_zs = ws[WS_BSTAR + HH + j];
        const float b_ni = ws[WS_BSTAR + 2 * HH + j];
        vb_r  = (f32x4){b_rs, b_rs, b_rs, b_rs};
        vb_z  = (f32x4){b_zs, b_zs, b_zs, b_zs};
        vb_nh = (f32x4){b_nh, b_nh, b_nh, b_nh};
        vb_ni = (f32x4){b_ni, b_ni, b_ni, b_ni};
        vb_o  = (f32x4){b_o,  b_o,  b_o,  b_o};
    }

    __syncthreads();   // step-0 h' visible to all waves

    // ================= steps: software-pipelined {phase2 || phase1} =======
    // body(qb): h_{s+1} in shb[qb]. Groups (sched_barrier separated):
    //   G0: phase2 MFMA + MT_MFMA(0) + MT_MFMA(1)   (fill MFMA pipe)
    //   G1: y-stores + ACT(0) || MT_MFMA(2)          (VALU under MFMA)
    //   G2: ACT(1) || MT_MFMA(3)
    //   G3: ACT(2) + ACT(3)
    auto body = [&](int qb, bool last) {
        const int rdoff = qb * BUFB;
        // ---- phase 2 MFMAs: y_s = h_{s+1} @ Wout^T + bout ----
        f32x4 yo;
        {
            bf16x8 Y0 = *(const bf16x8*)(shbb + rdoff + rb[0] + rowtile * 4096);
            bf16x8 Y1 = *(const bf16x8*)(shbb + rdoff + rb[1] + rowtile * 4096);
            bf16x8 Y2 = *(const bf16x8*)(shbb + rdoff + rb[2] + rowtile * 4096);
            bf16x8 Y3 = *(const bf16x8*)(shbb + rdoff + rb[3] + rowtile * 4096);
            yo = MFMA(Y0, Bo[0], vb_o);
            yo = MFMA(Y1, Bo[1], yo);
            yo = MFMA(Y2, Bo[2], yo);
            yo = MFMA(Y3, Bo[3], yo);
        }
        if (last) {
            yp0[0]        = yo[0];
            yp0[NSTEP*II] = yo[1];
            yp1[0]        = yo[2];
            yp1[NSTEP*II] = yo[3];
            return;
        }
        const int wroff = (qb ^ 1) * BUFB;

        f32x4 ar0, az0, anh0, ani0;
        f32x4 ar1, az1, anh1, ani1;
        MT_MFMA(0, ar0, az0, anh0, ani0, rdoff);
        MT_MFMA(1, ar1, az1, anh1, ani1, rdoff);
        SB();

        // G1: y stores + ACT(0) while MT(2) MFMAs occupy the matrix pipe
        f32x4 ar2, az2, anh2, ani2;
        MT_MFMA(2, ar2, az2, anh2, ani2, rdoff);
        yp0[0]        = yo[0];
        yp0[NSTEP*II] = yo[1];
        yp1[0]        = yo[2];
        yp1[NSTEP*II] = yo[3];
        yp0 += II;
        yp1 += II;
        ACT_MT(0, ar0, az0, anh0, ani0, wroff);
        SB();

        // G2: ACT(1) while MT(3) MFMAs run
        f32x4 ar3, az3, anh3, ani3;
        MT_MFMA(3, ar3, az3, anh3, ani3, rdoff);
        ACT_MT(1, ar1, az1, anh1, ani1, wroff);
        SB();

        // G3: drain
        ACT_MT(2, ar2, az2, anh2, ani2, wroff);
        ACT_MT(3, ar3, az3, anh3, ani3, wroff);
        LDS_BARRIER();
    };

    for (int s2 = 0; s2 < NSTEP - 2; s2 += 2) {   // s = 0..27
        body(1, false);
        body(0, false);
    }
    body(1, false);   // s = 28
    body(0, true);    // s = 29: final Y only
}

extern "C" void kernel_launch(void* const* d_in, const int* in_sizes, int n_in,
                              void* d_out, int out_size, void* d_ws, size_t ws_size,
                              hipStream_t stream) {
    (void)in_sizes; (void)n_in; (void)out_size; (void)ws_size;
    const float* x    = (const float*)d_in[0];
    const float* h0   = (const float*)d_in[1];
    const float* Wih  = (const float*)d_in[2];
    const float* Whh  = (const float*)d_in[3];
    const float* bih  = (const float*)d_in[4];
    const float* bhh  = (const float*)d_in[5];
    const float* Wout = (const float*)d_in[6];
    const float* bout = (const float*)d_in[7];
    float* out = (float*)d_out;
    float* ws  = (float*)d_ws;

    fold_kernel<<<dim3(384), dim3(128), 0, stream>>>(Wih, Whh, bih, bhh,
                                                     Wout, bout, ws);
    dim3 grid(NB / BM);   // 256 blocks -> 1 per CU (8 waves = 2 waves/SIMD)
    dim3 block(512);
    gru_mfma_kernel<<<grid, block, 0, stream>>>(x, h0, Wih, Whh, bih, bhh,
                                                Wout, bout, ws, out);
}